// Round 5
// baseline (87.891 us; speedup 1.0000x reference)
//
#include <hip/hip_runtime.h>
#include <stdint.h>

// Tropical (max-plus) matmul: Y[m][n] = max_k X[m][k] + W[n][k]
// M=512, N=1024, K=1024, fp32 in/out. (max,+) -> no MFMA, VALU only.
//
// R3 post-mortem: 8x4 micro with uint4 fragments needs ~80 live VGPRs; compiler
// clamped to 64 and rematerialized LDS reads as scalar ds_read_b32 per use
// (bank conflicts appeared, VALUBusy fell to 30%, 44us). R4/R5: k-major LDS
// layout, fragments are SCALAR uint32 packed-f16 words (12 live), loaded once
// per k-word and used immediately -> no remat incentive, ds_read2_b32-mergeable,
// conflict-free. Inner stays v_pk_add_f16/v_pk_max_f16 (2 k/instr).
// 128x64 tile, 256 thr, 8x4 micro, split-K S=16, partials + max-combine.

typedef _Float16 h1;
typedef _Float16 __attribute__((ext_vector_type(2))) h2;
typedef __fp16 __attribute__((ext_vector_type(2))) fp16x2;  // cvt_pkrtz return type

#define BM 128
#define BN 64
#define BK 32            // k-steps per tile
#define KW (BK / 2)      // packed k-words per tile = 16
#define XS_STRIDE (BM + 1)  // 129: pad breaks pow2 banking (writes 2-way = free)
#define WS_STRIDE (BN + 1)  // 65

#define M_DIM 512
#define N_DIM 1024
#define K_DIM 1024

__device__ __forceinline__ uint32_t pk_add(uint32_t a, uint32_t b) {
    uint32_t d;
    asm("v_pk_add_f16 %0, %1, %2" : "=v"(d) : "v"(a), "v"(b));
    return d;
}
__device__ __forceinline__ uint32_t pk_max(uint32_t a, uint32_t b) {
    uint32_t d;
    asm("v_pk_max_f16 %0, %1, %2" : "=v"(d) : "v"(a), "v"(b));
    return d;
}
__device__ __forceinline__ uint32_t pkrtz(float a, float b) {
    fp16x2 p = __builtin_amdgcn_cvt_pkrtz(a, b);
    return __builtin_bit_cast(uint32_t, p);
}

__global__ __launch_bounds__(256)
void tropical_mm_kmaj(const float* __restrict__ X, const float* __restrict__ W,
                      float* __restrict__ out, int Kper) {
    __shared__ uint32_t Xs[KW][XS_STRIDE];
    __shared__ uint32_t Ws[KW][WS_STRIDE];

    const int tid = threadIdx.x;
    const int tx = tid & 15;        // n = tx + 16j, j=0..3
    const int ty = tid >> 4;        // m = ty + 16i, i=0..7
    const int nb = blockIdx.x;      // 16 tiles of 64 cols
    const int mb = blockIdx.y;      // 4 tiles of 128 rows
    const int sb = blockIdx.z;      // split-K slice
    const int k0 = sb * Kper;

    const uint32_t NEGP = 0xFBFFFBFFu;  // packed (-65504, -65504)
    uint32_t acc[8][4];
#pragma unroll
    for (int i = 0; i < 8; i++)
#pragma unroll
        for (int j = 0; j < 4; j++) acc[i][j] = NEGP;

    // staging: thread -> (row srow, 8-float k-group) -> 4 packed words, k-major
    const int srow = tid >> 2;          // 0..63
    const int sfc  = (tid & 3) * 8;     // float col: 0,8,16,24
    const int w0   = (tid & 3) * 4;     // k-word: 0,4,8,12

    for (int kt = 0; kt < Kper; kt += BK) {
        const int kb = k0 + kt;
        // --- stage X (128 rows x 32 k): 2 rows/thread ---
        {
            const float* g = &X[(size_t)(mb * BM + srow) * K_DIM + kb + sfc];
            float4 f0 = *(const float4*)g;
            float4 f1 = *(const float4*)(g + 4);
            Xs[w0 + 0][srow] = pkrtz(f0.x, f0.y);
            Xs[w0 + 1][srow] = pkrtz(f0.z, f0.w);
            Xs[w0 + 2][srow] = pkrtz(f1.x, f1.y);
            Xs[w0 + 3][srow] = pkrtz(f1.z, f1.w);

            const float* g2 = &X[(size_t)(mb * BM + srow + 64) * K_DIM + kb + sfc];
            float4 f2 = *(const float4*)g2;
            float4 f3 = *(const float4*)(g2 + 4);
            Xs[w0 + 0][srow + 64] = pkrtz(f2.x, f2.y);
            Xs[w0 + 1][srow + 64] = pkrtz(f2.z, f2.w);
            Xs[w0 + 2][srow + 64] = pkrtz(f3.x, f3.y);
            Xs[w0 + 3][srow + 64] = pkrtz(f3.z, f3.w);
        }
        // --- stage W (64 rows x 32 k): 1 row/thread ---
        {
            const float* g = &W[(size_t)(nb * BN + srow) * K_DIM + kb + sfc];
            float4 f0 = *(const float4*)g;
            float4 f1 = *(const float4*)(g + 4);
            Ws[w0 + 0][srow] = pkrtz(f0.x, f0.y);
            Ws[w0 + 1][srow] = pkrtz(f0.z, f0.w);
            Ws[w0 + 2][srow] = pkrtz(f1.x, f1.y);
            Ws[w0 + 3][srow] = pkrtz(f1.z, f1.w);
        }
        __syncthreads();

        // --- compute: per k-word, scalar fragments (12 live regs), 32 pk pairs ---
#pragma unroll 4
        for (int w = 0; w < KW; w++) {
            uint32_t ww[4];
#pragma unroll
            for (int j = 0; j < 4; j++) ww[j] = Ws[w][tx + 16 * j];
            uint32_t xw[8];
#pragma unroll
            for (int i = 0; i < 8; i++) xw[i] = Xs[w][ty + 16 * i];
#pragma unroll
            for (int i = 0; i < 8; i++)
#pragma unroll
                for (int j = 0; j < 4; j++)
                    acc[i][j] = pk_max(acc[i][j], pk_add(xw[i], ww[j]));
        }
        __syncthreads();
    }

    // epilogue: fold packed k-parity lanes to fp32, write partial slice
    float* dst = out + (size_t)sb * M_DIM * N_DIM;
#pragma unroll
    for (int i = 0; i < 8; i++) {
        const int m = mb * BM + ty + 16 * i;
#pragma unroll
        for (int j = 0; j < 4; j++) {
            const int n = nb * BN + tx + 16 * j;
            h2 v = __builtin_bit_cast(h2, acc[i][j]);
            dst[(size_t)m * N_DIM + n] = fmaxf((float)v[0], (float)v[1]);
        }
    }
}

__global__ __launch_bounds__(256)
void combine_max_kernel(const float* __restrict__ part, float* __restrict__ out, int S) {
    const int idx = blockIdx.x * blockDim.x + threadIdx.x;  // over float4s
    const size_t stride = (size_t)M_DIM * N_DIM;
    float4 a = ((const float4*)part)[idx];
    for (int s = 1; s < S; s++) {
        float4 b = ((const float4*)(part + (size_t)s * stride))[idx];
        a.x = fmaxf(a.x, b.x);
        a.y = fmaxf(a.y, b.y);
        a.z = fmaxf(a.z, b.z);
        a.w = fmaxf(a.w, b.w);
    }
    ((float4*)out)[idx] = a;
}

extern "C" void kernel_launch(void* const* d_in, const int* in_sizes, int n_in,
                              void* d_out, int out_size, void* d_ws, size_t ws_size,
                              hipStream_t stream) {
    const float* X = (const float*)d_in[0];   // [512][1024]
    const float* W = (const float*)d_in[1];   // [1024][1024]
    float* out = (float*)d_out;               // [512][1024]

    const size_t slice_bytes = (size_t)M_DIM * N_DIM * sizeof(float);  // 2 MB

    int S;
    if (ws_size >= 16 * slice_bytes)     S = 16;
    else if (ws_size >= 8 * slice_bytes) S = 8;
    else if (ws_size >= 4 * slice_bytes) S = 4;
    else if (ws_size >= 2 * slice_bytes) S = 2;
    else                                 S = 1;

    const int Kper = K_DIM / S;
    float* target = (S == 1) ? out : (float*)d_ws;

    dim3 grid(N_DIM / BN, M_DIM / BM, S);  // 16 x 4 x S -> 1024 blocks at S=16
    tropical_mm_kmaj<<<grid, 256, 0, stream>>>(X, W, target, Kper);

    if (S > 1) {
        const int n4 = M_DIM * N_DIM / 4;  // 131072 float4
        combine_max_kernel<<<n4 / 256, 256, 0, stream>>>((const float*)d_ws, out, S);
    }
}

// Round 6
// 87.392 us; speedup vs baseline: 1.0057x; 1.0057x over previous
//
#include <hip/hip_runtime.h>
#include <stdint.h>

// Tropical (max-plus) matmul: Y[m][n] = max_k X[m][k] + W[n][k]
// M=512, N=1024, K=1024, fp32 in/out. (max,+) -> no MFMA, VALU only.
//
// R5 post-mortem: scalar ds_read_b32 fragments -> DS-pipe instr-bound
// (~1.6M b32 at 5.8cyc = 15us floor, ~40% latency eff -> 40us).
// R6: chunk-major LDS (Xs[chunk][m][4words]) -> ds_read_b128 fragments
// (12 per 8 k-steps), DS floor ~7.7us. __launch_bounds__(256,4) = 128-VGPR
// cap so the 96-reg live set fits WITHOUT the R3 remat pathology; S=16 ->
// 1024 blocks = 4/CU = 16 waves/CU for latency hiding. Inner semiring stays
// inline-asm v_pk_add_f16 / v_pk_max_f16 (2 k per instr).

typedef _Float16 h1;
typedef _Float16 __attribute__((ext_vector_type(2))) h2;
typedef __fp16 __attribute__((ext_vector_type(2))) fp16x2;  // cvt_pkrtz return type

#define BM 128
#define BN 64
#define BK 32    // k-steps per tile
#define NCH 4    // chunks per tile; 1 chunk = 4 packed words = 8 k-steps

#define M_DIM 512
#define N_DIM 1024
#define K_DIM 1024

__device__ __forceinline__ uint32_t pk_add(uint32_t a, uint32_t b) {
    uint32_t d;
    asm("v_pk_add_f16 %0, %1, %2" : "=v"(d) : "v"(a), "v"(b));
    return d;
}
__device__ __forceinline__ uint32_t pk_max(uint32_t a, uint32_t b) {
    uint32_t d;
    asm("v_pk_max_f16 %0, %1, %2" : "=v"(d) : "v"(a), "v"(b));
    return d;
}
__device__ __forceinline__ uint32_t pkrtz(float a, float b) {
    fp16x2 p = __builtin_amdgcn_cvt_pkrtz(a, b);
    return __builtin_bit_cast(uint32_t, p);
}

__global__ __launch_bounds__(256, 4)
void tropical_mm_chunk(const float* __restrict__ X, const float* __restrict__ W,
                       float* __restrict__ out, int Kper) {
    // chunk-major: fragment loads are ds_read_b128; no padding needed
    // (X reads 16-lane broadcast; W reads 2-way = free; b128 staging writes
    // spread perfectly over all 32 banks).
    __shared__ uint32_t Xs[NCH][BM][4];   // 8 KB
    __shared__ uint32_t Ws[NCH][BN][4];   // 4 KB

    const int tid = threadIdx.x;
    const int tx = tid & 15;        // n = tx + 16j, j=0..3
    const int ty = tid >> 4;        // m = ty + 16i, i=0..7
    const int nb = blockIdx.x;      // 16 tiles of 64 cols
    const int mb = blockIdx.y;      // 4 tiles of 128 rows
    const int sb = blockIdx.z;      // split-K slice
    const int k0 = sb * Kper;

    const uint32_t NEGP = 0xFBFFFBFFu;  // packed (-65504, -65504)
    uint32_t acc[8][4];
#pragma unroll
    for (int i = 0; i < 8; i++)
#pragma unroll
        for (int j = 0; j < 4; j++) acc[i][j] = NEGP;

    // staging: thread -> (row srow, chunk c); 8 floats -> one uint4
    const int srow = tid >> 2;          // 0..63
    const int c    = tid & 3;           // chunk 0..3
    const int sfc  = c * 8;             // float col within tile

    for (int kt = 0; kt < Kper; kt += BK) {
        const int kb = k0 + kt;
        // --- stage X (128 rows x 32 k): rows srow and srow+64 ---
        {
            const float* g = &X[(size_t)(mb * BM + srow) * K_DIM + kb + sfc];
            float4 f0 = *(const float4*)g;
            float4 f1 = *(const float4*)(g + 4);
            uint4 v = {pkrtz(f0.x, f0.y), pkrtz(f0.z, f0.w),
                       pkrtz(f1.x, f1.y), pkrtz(f1.z, f1.w)};
            *(uint4*)&Xs[c][srow][0] = v;

            const float* g2 = &X[(size_t)(mb * BM + srow + 64) * K_DIM + kb + sfc];
            float4 f2 = *(const float4*)g2;
            float4 f3 = *(const float4*)(g2 + 4);
            uint4 v2 = {pkrtz(f2.x, f2.y), pkrtz(f2.z, f2.w),
                        pkrtz(f3.x, f3.y), pkrtz(f3.z, f3.w)};
            *(uint4*)&Xs[c][srow + 64][0] = v2;
        }
        // --- stage W (64 rows x 32 k) ---
        {
            const float* g = &W[(size_t)(nb * BN + srow) * K_DIM + kb + sfc];
            float4 f0 = *(const float4*)g;
            float4 f1 = *(const float4*)(g + 4);
            uint4 v = {pkrtz(f0.x, f0.y), pkrtz(f0.z, f0.w),
                       pkrtz(f1.x, f1.y), pkrtz(f1.z, f1.w)};
            *(uint4*)&Ws[c][srow][0] = v;
        }
        __syncthreads();

        // --- compute: per chunk (8 k-steps), 12 ds_read_b128 + 256 pk instrs ---
#pragma unroll 1
        for (int ch = 0; ch < NCH; ch++) {
            uint4 wf[4], xf[8];
#pragma unroll
            for (int j = 0; j < 4; j++) wf[j] = *(const uint4*)&Ws[ch][tx + 16 * j][0];
#pragma unroll
            for (int i = 0; i < 8; i++) xf[i] = *(const uint4*)&Xs[ch][ty + 16 * i][0];
#pragma unroll
            for (int i = 0; i < 8; i++) {
#pragma unroll
                for (int j = 0; j < 4; j++) {
                    uint32_t t0 = pk_add(xf[i].x, wf[j].x);
                    uint32_t t1 = pk_add(xf[i].y, wf[j].y);
                    uint32_t t2 = pk_add(xf[i].z, wf[j].z);
                    uint32_t t3 = pk_add(xf[i].w, wf[j].w);
                    uint32_t m = pk_max(pk_max(t0, t1), pk_max(t2, t3));
                    acc[i][j] = pk_max(acc[i][j], m);
                }
            }
        }
        __syncthreads();
    }

    // epilogue: fold packed k-parity lanes to fp32, write partial slice
    float* dst = out + (size_t)sb * M_DIM * N_DIM;
#pragma unroll
    for (int i = 0; i < 8; i++) {
        const int m = mb * BM + ty + 16 * i;
#pragma unroll
        for (int j = 0; j < 4; j++) {
            const int n = nb * BN + tx + 16 * j;
            h2 v = __builtin_bit_cast(h2, acc[i][j]);
            dst[(size_t)m * N_DIM + n] = fmaxf((float)v[0], (float)v[1]);
        }
    }
}

__global__ __launch_bounds__(256)
void combine_max_kernel(const float* __restrict__ part, float* __restrict__ out, int S) {
    const int idx = blockIdx.x * blockDim.x + threadIdx.x;  // over float4s
    const size_t stride = (size_t)M_DIM * N_DIM;
    float4 a = ((const float4*)part)[idx];
    for (int s = 1; s < S; s++) {
        float4 b = ((const float4*)(part + (size_t)s * stride))[idx];
        a.x = fmaxf(a.x, b.x);
        a.y = fmaxf(a.y, b.y);
        a.z = fmaxf(a.z, b.z);
        a.w = fmaxf(a.w, b.w);
    }
    ((float4*)out)[idx] = a;
}

extern "C" void kernel_launch(void* const* d_in, const int* in_sizes, int n_in,
                              void* d_out, int out_size, void* d_ws, size_t ws_size,
                              hipStream_t stream) {
    const float* X = (const float*)d_in[0];   // [512][1024]
    const float* W = (const float*)d_in[1];   // [1024][1024]
    float* out = (float*)d_out;               // [512][1024]

    const size_t slice_bytes = (size_t)M_DIM * N_DIM * sizeof(float);  // 2 MB

    int S;
    if (ws_size >= 16 * slice_bytes)     S = 16;  // 1024 blocks = 4/CU
    else if (ws_size >= 8 * slice_bytes) S = 8;
    else if (ws_size >= 4 * slice_bytes) S = 4;
    else if (ws_size >= 2 * slice_bytes) S = 2;
    else                                 S = 1;

    const int Kper = K_DIM / S;
    float* target = (S == 1) ? out : (float*)d_ws;

    dim3 grid(N_DIM / BN, M_DIM / BM, S);  // 16 x 4 x S
    tropical_mm_chunk<<<grid, 256, 0, stream>>>(X, W, target, Kper);

    if (S > 1) {
        const int n4 = M_DIM * N_DIM / 4;  // 131072 float4
        combine_max_kernel<<<n4 / 256, 256, 0, stream>>>((const float*)d_ws, out, S);
    }
}